// Round 10
// baseline (171.804 us; speedup 1.0000x reference)
//
#include <hip/hip_runtime.h>
#include <math.h>

constexpr int NN = 4000;
constexpr int EE = 48000;
constexpr int ZZ = 10;
constexpr float RMAX = 5.0f;
constexpr float INV_AVG = 1.0f / 12.0f;

// geom role-block layout
constexpr int GB_EDGE = 188;          // [0,188)   edges
constexpr int GB_SPEC = GB_EDGE + 16; // [188,204) species
constexpr int GB_W3Z  = GB_SPEC + 32; // [204,236) Wm3 l=0 gather
constexpr int GB_T0   = GB_W3Z + 3;   // [236,239) per-species tables
constexpr int GB_ZERO = GB_T0 + 64;   // [239,303) zero agg0/agg1/ghb + out force region
constexpr int ZWS_F4  = 3*NN*64/4;
constexpr int ZOUT_F4 = 3*NN/4;

__device__ __forceinline__ float rl(float v, int lane){
    return __uint_as_float(__builtin_amdgcn_readlane(__float_as_uint(v), lane));
}
__device__ __forceinline__ float sigf(float x){ return 1.0f/(1.0f+__expf(-x)); }
__device__ __forceinline__ float siluf(float x){ return x*sigf(x); }
__device__ __forceinline__ float dsiluf(float x){ float s=sigf(x); return s*(1.0f+x*(1.0f-s)); }

__device__ __forceinline__ void pin64(float (&W)[64]){
#pragma unroll
    for (int i=0;i<64;i++) asm volatile("" : "+v"(W[i]));
}
__device__ __forceinline__ void pin8(float (&W)[8]){
#pragma unroll
    for (int i=0;i<8;i++) asm volatile("" : "+v"(W[i]));
}

// readlane broadcast matvec (VALU pipe only)
__device__ __forceinline__ float bmv64(float src, const float (&W)[64]){
    float a0=0.f,a1=0.f,a2=0.f,a3=0.f;
#pragma unroll
    for (int k=0;k<64;k+=4){
        a0 += rl(src,k+0)*W[k+0];
        a1 += rl(src,k+1)*W[k+1];
        a2 += rl(src,k+2)*W[k+2];
        a3 += rl(src,k+3)*W[k+3];
    }
    return (a0+a1)+(a2+a3);
}
// wave-uniform activation pointer: s_load + v_fmac(s, v) — no broadcast at all
__device__ __forceinline__ float bmv_s(const float* act, const float (&W)[64]){
    float a0=0.f,a1=0.f,a2=0.f,a3=0.f;
#pragma unroll
    for (int k=0;k<64;k+=4){
        a0 += act[k+0]*W[k+0];
        a1 += act[k+1]*W[k+1];
        a2 += act[k+2]*W[k+2];
        a3 += act[k+3]*W[k+3];
    }
    return (a0+a1)+(a2+a3);
}
// per-lane value broadcast via per-wave LDS slice
__device__ __forceinline__ float bmv_lds(float v, const float (&W)[64], float* slice, int lane){
    slice[lane] = v;
    float a0=0.f,a1=0.f,a2=0.f,a3=0.f;
#pragma unroll
    for (int k=0;k<64;k+=4){
        float4 a = *reinterpret_cast<const float4*>(slice + k);
        a0 += a.x*W[k+0];
        a1 += a.y*W[k+1];
        a2 += a.z*W[k+2];
        a3 += a.w*W[k+3];
    }
    return (a0+a1)+(a2+a3);
}
__device__ __forceinline__ void load_row64(const float* __restrict__ p, float (&W)[64]){
#pragma unroll
    for (int i=0;i<16;i++){
        float4 v = reinterpret_cast<const float4*>(p)[i];
        W[4*i]=v.x; W[4*i+1]=v.y; W[4*i+2]=v.z; W[4*i+3]=v.w;
    }
}
__device__ __forceinline__ void load_col64(const float* __restrict__ p, int lane, float (&W)[64]){
#pragma unroll
    for (int k=0;k<64;k++) W[k] = p[k*64+lane];
}

// ---------------- tiny zero ----------------
__global__ void k_zero(int* __restrict__ ecount, float* __restrict__ out)
{
    int t = threadIdx.x;
    if (t < 8) out[t] = 0.0f;
    if (t == 8) *ecount = 0;
}

// ---------------- geometry/compaction + spec + precompute + big zero ----------------
__global__ void k_geom(const float* __restrict__ pos, const float* __restrict__ shifts,
                       const int* __restrict__ ei, const float* __restrict__ x,
                       const float* __restrict__ WE, const float* __restrict__ W_up,
                       const float* __restrict__ W_sc, const float* __restrict__ a_sc,
                       const float* __restrict__ Wm3,
                       int* __restrict__ spec,
                       float* __restrict__ u3c, float* __restrict__ frc, float* __restrict__ dfrc,
                       int* __restrict__ esrc, int* __restrict__ edst, int* __restrict__ ecount,
                       float* __restrict__ T0, float* __restrict__ SC0, float* __restrict__ W3z,
                       float4* __restrict__ zws, float* __restrict__ out)
{
    int b = blockIdx.x;
    if (b >= GB_ZERO) return;
    if (b >= GB_T0){
        float4 z4 = make_float4(0.f,0.f,0.f,0.f);
        float4* zout = (float4*)(out + 8 + NN);
        for (int i=(b-GB_T0)*256 + threadIdx.x; i < ZWS_F4 + ZOUT_F4; i += 64*256){
            if (i < ZWS_F4) zws[i] = z4;
            else zout[i-ZWS_F4] = z4;
        }
        return;
    }
    if (b >= GB_W3Z){
        int wv = (b-GB_W3Z)*4 + (threadIdx.x>>6);
        int lane = threadIdx.x & 63;
        if (wv < ZZ){
            float wev = WE[wv*64 + lane];
            float t=0.f, sc=0.f;
#pragma unroll
            for (int c=0;c<64;c++){
                float w = rl(wev,c);
                t  += w*W_up[c*64+lane];
                sc += w*W_sc[c*64+lane];
            }
            T0[wv*64+lane]  = t;
            SC0[wv*64+lane] = sc * a_sc[wv*64+lane];
        }
        return;
    }
    if (b >= GB_SPEC){
        int idx = (b-GB_SPEC)*256 + threadIdx.x;
        int l = idx >> 12;
        int kc = idx & 4095;
        int k = kc >> 6, c = kc & 63;
        W3z[idx] = Wm3[l*64*256 + k*256 + 4*c];
        return;
    }
    if (b >= GB_EDGE){
        int n = (b-GB_EDGE)*256 + threadIdx.x;
        if (n < NN){
            int sp = 0;
#pragma unroll
            for (int j=0;j<ZZ;j++) if (x[n*ZZ+j] > 0.5f) sp = j;
            spec[n] = sp;
        }
        return;
    }
    int e = b*256 + threadIdx.x;
    if (e >= EE) return;
    int s = ei[e], r = ei[EE+e];
    float vx = pos[r*3+0]-pos[s*3+0]+shifts[e*3+0];
    float vy = pos[r*3+1]-pos[s*3+1]+shifts[e*3+1];
    float vz = pos[r*3+2]-pos[s*3+2]+shifts[e*3+2];
    float rr = sqrtf(vx*vx+vy*vy+vz*vz);
    float u = rr*(1.0f/RMAX);
    if (u >= 1.0f) return;
    int slot = atomicAdd(ecount, 1);
    esrc[slot]=s; edst[slot]=r;
    float inv = 1.0f/rr;
    u3c[slot*3+0]=vx*inv; u3c[slot*3+1]=vy*inv; u3c[slot*3+2]=vz*inv;
    float u2=u*u, u4=u2*u2, u5=u4*u;
    float env  = 1.0f - 21.0f*u5 + 35.0f*u5*u - 15.0f*u5*u2;
    float om   = 1.0f-u;
    float denv = -21.0f*u4*om*om;
    const float A = 0.6324555320336759f;
    const float K1 = 3.14159265358979f/RMAX;
    float a  = K1*rr;
    float s1 = __sinf(a), c1 = __cosf(a);
    float sp = 0.0f, cp = 1.0f, sn = s1, cn = c1;
#pragma unroll
    for (int n=1;n<=8;n++){
        float k = (float)n*K1;
        float bess  = A*sn*inv;
        float dbess = A*(k*cn - sn*inv)*inv;
        frc [slot*8+n-1] = bess*env;
        dfrc[slot*8+n-1] = dbess*env + bess*denv;
        float s2 = 2.0f*c1*sn - sp; sp=sn; sn=s2;
        float c2 = 2.0f*c1*cn - cp; cp=cn; cn=c2;
    }
}

// ---------------- edge MLP forward, ILP-2 (two edges per iteration) ----------------
template<int L>
__global__ __launch_bounds__(256,2)
void k_edge_fwd(const float* __restrict__ frc, const int* __restrict__ esrc,
                const int* __restrict__ edst, const int* __restrict__ ecount,
                const int* __restrict__ spec, const float* __restrict__ T0,
                const float* __restrict__ h1,
                const float* __restrict__ W1, const float* __restrict__ W2,
                const float* __restrict__ W3z,
                float* __restrict__ agg, float* __restrict__ t2b,
                float* __restrict__ w0b)
{
    int lane = threadIdx.x & 63;
    int wid  = (blockIdx.x*256 + threadIdx.x) >> 6;
    int nw   = gridDim.x*4;
    int cnt  = ecount[0];
    float W1c[8], W2c[64], W3c[64];
#pragma unroll
    for (int j=0;j<8;j++) W1c[j] = W1[j*64+lane];
    load_col64(W2,  lane, W2c);
    load_col64(W3z, lane, W3c);
    pin8(W1c); pin64(W2c); pin64(W3c);
    for (int slot=wid; slot<cnt; slot+=2*nw){
        int usA = __builtin_amdgcn_readfirstlane(slot);
        int slotB = slot + nw;
        bool vB = slotB < cnt;
        int usB = __builtin_amdgcn_readfirstlane(vB ? slotB : slot);
        int sA = esrc[usA], rA = edst[usA];
        int sB = esrc[usB], rB = edst[usB];
        const float* fA = frc + usA*8;      // uniform -> s_load
        const float* fB = frc + usB*8;
        float t1A=0.f, t1B=0.f;
#pragma unroll
        for (int j=0;j<8;j++){ t1A += fA[j]*W1c[j]; t1B += fB[j]*W1c[j]; }
        float a1A = siluf(t1A), a1B = siluf(t1B);
        float t2A = bmv64(a1A, W2c);
        float t2B = bmv64(a1B, W2c);
        t2b[(size_t)usA*64+lane] = t2A;
        if (vB) t2b[(size_t)usB*64+lane] = t2B;
        float a2A = siluf(t2A), a2B = siluf(t2B);
        float w0A = bmv64(a2A, W3c);
        float w0B = bmv64(a2B, W3c);
        if (L==1){
            w0b[(size_t)usA*64+lane] = w0A;
            if (vB) w0b[(size_t)usB*64+lane] = w0B;
        }
        float hA = (L==0) ? T0[spec[sA]*64+lane] : h1[sA*64+lane];
        float hB = (L==0) ? T0[spec[sB]*64+lane] : h1[sB*64+lane];
        atomicAdd(&agg[rA*64+lane], w0A*hA*INV_AVG);
        if (vB) atomicAdd(&agg[rB*64+lane], w0B*hB*INV_AVG);
    }
}

// ---------------- node fwd layer0 ----------------
__global__ __launch_bounds__(256,2)
void k_node_fwd0(const float* __restrict__ agg, const float* __restrict__ SC0,
                 const int* __restrict__ spec, const int* __restrict__ batch,
                 const float* __restrict__ Wout, const float* __restrict__ Wprod,
                 const float* __restrict__ Wup1, const float* __restrict__ poly,
                 const float* __restrict__ wr0,
                 float* __restrict__ s0, float* __restrict__ nf1,
                 float* __restrict__ h1, float* __restrict__ out)
{
    __shared__ float part[8];
    __shared__ float sact[4][64];
    if (threadIdx.x < 8) part[threadIdx.x] = 0.f;
    __syncthreads();
    int lane = threadIdx.x & 63;
    float* slice = sact[threadIdx.x>>6];
    int wid = (blockIdx.x*256 + threadIdx.x) >> 6;
    int nw  = gridDim.x*4;
    float WA[64], WB[64], WC[64];
    load_col64(Wout, lane, WA);
    load_col64(Wprod,lane, WB);
    load_col64(Wup1, lane, WC);
    pin64(WA); pin64(WB); pin64(WC);
    float p0=poly[lane], p1=poly[64+lane], p2=poly[128+lane];
    float w0r = wr0[lane];
    for (int nn=wid; nn<NN; nn+=nw){
        int n = __builtin_amdgcn_readfirstlane(nn);
        const float* an = agg + n*64;          // uniform -> s_load
        float s  = bmv_s(an, WA);
        float gate = p0 + p1*s + p2*s*s;
        float nf = bmv_lds(s*gate, WB, slice, lane) + SC0[spec[n]*64+lane];
        s0 [n*64+lane] = s;
        nf1[n*64+lane] = nf;
        h1 [n*64+lane] = bmv_lds(nf, WC, slice, lane);
        float ne = nf*w0r;
#pragma unroll
        for (int off=32;off;off>>=1) ne += __shfl_xor(ne,off);
        if (lane==0){ out[8+n] = ne; atomicAdd(&part[batch[n]], ne); }
    }
    __syncthreads();
    if (threadIdx.x < 8) atomicAdd(&out[threadIdx.x], part[threadIdx.x]);
}

// ---------------- FUSED layer1: node fwd + readout fwd/bwd + node bwd ----------------
__global__ __launch_bounds__(256,2)
void k_node1(const float* __restrict__ agg, const float* __restrict__ nf1,
             const int* __restrict__ spec, const int* __restrict__ batch,
             const float* __restrict__ Wout, const float* __restrict__ Wprod,
             const float* __restrict__ Wsc, const float* __restrict__ asc,
             const float* __restrict__ poly, const float* __restrict__ Wr1,
             const float* __restrict__ wr2,
             float* __restrict__ out, float* __restrict__ gagg, float* __restrict__ gacc)
{
    __shared__ float part[8];
    __shared__ float sact[4][64];
    if (threadIdx.x < 8) part[threadIdx.x] = 0.f;
    __syncthreads();
    int lane = threadIdx.x & 63;
    float* slice = sact[threadIdx.x>>6];
    int wid = (blockIdx.x*256 + threadIdx.x) >> 6;   // 0..1999
    int na = __builtin_amdgcn_readfirstlane(wid);
    int nb = na + 2000;
    int spA = spec[na], spB = spec[nb];
    float p0=poly[lane], p1=poly[64+lane], p2=poly[128+lane];
    float WA[64], WB[64], WC[64];
    // ---- phase 1: node fwd (col-form) ----
    load_col64(Wout, lane, WA);
    load_col64(Wprod,lane, WB);
    load_col64(Wsc,  lane, WC);
    pin64(WA); pin64(WB); pin64(WC);
    float sA = bmv_s(agg + na*64, WA);
    float sB = bmv_s(agg + nb*64, WA);
    float scpA = bmv_s(nf1 + na*64, WC);
    float scpB = bmv_s(nf1 + nb*64, WC);
    float gateA = p0 + p1*sA + p2*sA*sA;
    float gateB = p0 + p1*sB + p2*sB*sB;
    float nfA = bmv_lds(sA*gateA, WB, slice, lane) + scpA*asc[spA*64+lane];
    float nfB = bmv_lds(sB*gateB, WB, slice, lane) + scpB*asc[spB*64+lane];
    // ---- phase 2: readout fwd + bwd ----
    int j = lane & 15;
    float w2 = wr2[j];
#pragma unroll
    for (int c=0;c<64;c++) WA[c] = Wr1[c*16 + j];
    pin64(WA);
    float Wrow[16];
#pragma unroll
    for (int i2=0;i2<4;i2++){
        float4 v = reinterpret_cast<const float4*>(Wr1 + lane*16)[i2];
        Wrow[4*i2]=v.x; Wrow[4*i2+1]=v.y; Wrow[4*i2+2]=v.z; Wrow[4*i2+3]=v.w;
    }
    float gA, gB;
    {
        float z  = bmv_lds(nfA, WA, slice, lane);
        float ne = siluf(z)*w2;
#pragma unroll
        for (int off=32;off;off>>=1) ne += __shfl_xor(ne,off);
        ne *= 0.25f;
        float gz = w2*dsiluf(z);
        slice[lane] = gz;
        float g = 0.f;
#pragma unroll
        for (int jj=0;jj<16;jj+=4){
            float4 a = *reinterpret_cast<const float4*>(slice + jj);
            g += a.x*Wrow[jj] + a.y*Wrow[jj+1] + a.z*Wrow[jj+2] + a.w*Wrow[jj+3];
        }
        gA = g;
        if (lane==0){ out[8+na] += ne; atomicAdd(&part[batch[na]], ne); }
    }
    {
        float z  = bmv_lds(nfB, WA, slice, lane);
        float ne = siluf(z)*w2;
#pragma unroll
        for (int off=32;off;off>>=1) ne += __shfl_xor(ne,off);
        ne *= 0.25f;
        float gz = w2*dsiluf(z);
        slice[lane] = gz;
        float g = 0.f;
#pragma unroll
        for (int jj=0;jj<16;jj+=4){
            float4 a = *reinterpret_cast<const float4*>(slice + jj);
            g += a.x*Wrow[jj] + a.y*Wrow[jj+1] + a.z*Wrow[jj+2] + a.w*Wrow[jj+3];
        }
        gB = g;
        if (lane==0){ out[8+nb] += ne; atomicAdd(&part[batch[nb]], ne); }
    }
    // ---- phase 3: node bwd (row-form) ----
    load_row64(Wprod + lane*64, WA);
    load_row64(Wout  + lane*64, WB);
    load_row64(Wsc   + lane*64, WC);
    pin64(WA); pin64(WB); pin64(WC);
    {
        float gv = bmv_lds(gA, WA, slice, lane);
        float gs = gv*(gateA + sA*(p1 + 2.0f*p2*sA));
        gagg[na*64+lane] = bmv_lds(gs, WB, slice, lane);
        gacc[na*64+lane] = bmv_lds(gA*asc[spA*64+lane], WC, slice, lane);
    }
    {
        float gv = bmv_lds(gB, WA, slice, lane);
        float gs = gv*(gateB + sB*(p1 + 2.0f*p2*sB));
        gagg[nb*64+lane] = bmv_lds(gs, WB, slice, lane);
        gacc[nb*64+lane] = bmv_lds(gB*asc[spB*64+lane], WC, slice, lane);
    }
    __syncthreads();
    if (threadIdx.x < 8) atomicAdd(&out[threadIdx.x], part[threadIdx.x]);
}

// ---------------- fused gnf1 assembly + node bwd layer0 ----------------
__global__ __launch_bounds__(256,2)
void k_bnode0(const float* __restrict__ ghb, const float* __restrict__ gacc,
              const float* __restrict__ Wup1, const float* __restrict__ wr0,
              const float* __restrict__ sbuf, const float* __restrict__ Wout,
              const float* __restrict__ Wprod, const float* __restrict__ poly,
              float* __restrict__ gagg)
{
    __shared__ float sact[4][64];
    int lane = threadIdx.x & 63;
    float* slice = sact[threadIdx.x>>6];
    int wid = (blockIdx.x*256 + threadIdx.x) >> 6;
    int nw  = gridDim.x*4;
    float Ur[64], Pr[64], Or[64];
    load_row64(Wup1 + lane*64, Ur);
    load_row64(Wprod+ lane*64, Pr);
    load_row64(Wout + lane*64, Or);
    pin64(Ur); pin64(Pr); pin64(Or);
    float p0=poly[lane], p1=poly[64+lane], p2=poly[128+lane];
    float w0r = wr0[lane];
    for (int nn=wid; nn<NN; nn+=nw){
        int n = __builtin_amdgcn_readfirstlane(nn);
        const float* ghn = ghb + n*64;         // uniform
        float g  = bmv_s(ghn, Ur) + gacc[n*64+lane] + w0r;
        float gv = bmv_lds(g, Pr, slice, lane);
        float s  = sbuf[n*64+lane];
        float gate = p0 + p1*s + p2*s*s;
        float gs = gv*(gate + s*(p1 + 2.0f*p2*s));
        gagg[n*64+lane] = bmv_lds(gs, Or, slice, lane);
    }
}

// ---------------- edge bwd, ILP-2 ----------------
template<int L>
__global__ __launch_bounds__(256,2)
void k_edge_bwd(const float* __restrict__ frc, const float* __restrict__ dfrc,
                const float* __restrict__ u3c, const int* __restrict__ esrc,
                const int* __restrict__ edst, const int* __restrict__ ecount,
                const int* __restrict__ spec, const float* __restrict__ T0,
                const float* __restrict__ h1, const float* __restrict__ gagg,
                const float* __restrict__ t2b, const float* __restrict__ w0b,
                const float* __restrict__ W1, const float* __restrict__ W2,
                const float* __restrict__ W3z,
                float* __restrict__ ghb, float* __restrict__ out)
{
    int lane = threadIdx.x & 63;
    int wid  = (blockIdx.x*256 + threadIdx.x) >> 6;
    int nw   = gridDim.x*4;
    int cnt  = ecount[0];
    float* outf = out + 8 + NN;
    float W3r[64], W2r[64], W1c[8];
    load_row64(W3z + lane*64, W3r);
    load_row64(W2  + lane*64, W2r);
#pragma unroll
    for (int j=0;j<8;j++) W1c[j] = W1[j*64+lane];
    pin64(W3r); pin64(W2r); pin8(W1c);
    for (int slot=wid; slot<cnt; slot+=2*nw){
        int usA = __builtin_amdgcn_readfirstlane(slot);
        int slotB = slot + nw;
        bool vB = slotB < cnt;
        int usB = __builtin_amdgcn_readfirstlane(vB ? slotB : slot);
        int sA = esrc[usA], rA = edst[usA];
        int sB = esrc[usB], rB = edst[usB];
        float gmA = gagg[rA*64+lane]*INV_AVG;
        float gmB = gagg[rB*64+lane]*INV_AVG;
        float hA  = (L==0) ? T0[spec[sA]*64+lane] : h1[sA*64+lane];
        float hB  = (L==0) ? T0[spec[sB]*64+lane] : h1[sB*64+lane];
        if (L==1){
            atomicAdd(&ghb[sA*64+lane], gmA*w0b[(size_t)usA*64+lane]);
            if (vB) atomicAdd(&ghb[sB*64+lane], gmB*w0b[(size_t)usB*64+lane]);
        }
        float ga2A = bmv64(gmA*hA, W3r);
        float ga2B = bmv64(gmB*hB, W3r);
        float gt2A = ga2A*dsiluf(t2b[(size_t)usA*64+lane]);
        float gt2B = ga2B*dsiluf(t2b[(size_t)usB*64+lane]);
        float ga1A = bmv64(gt2A, W2r);
        float ga1B = bmv64(gt2B, W2r);
        const float* fA  = frc  + usA*8;       // uniform
        const float* dfA = dfrc + usA*8;
        const float* fB  = frc  + usB*8;
        const float* dfB = dfrc + usB*8;
        float t1A=0.f, wdA=0.f, t1B=0.f, wdB=0.f;
#pragma unroll
        for (int j=0;j<8;j++){
            t1A += fA[j]*W1c[j]; wdA += dfA[j]*W1c[j];
            t1B += fB[j]*W1c[j]; wdB += dfB[j]*W1c[j];
        }
        float pA = ga1A*dsiluf(t1A)*wdA;
        float pB = ga1B*dsiluf(t1B)*wdB;
#pragma unroll
        for (int off=32;off;off>>=1){ pA += __shfl_xor(pA,off); pB += __shfl_xor(pB,off); }
        if (lane<3) atomicAdd(&outf[rA*3+lane], -u3c[usA*3+lane]*pA);
        else if (lane>=32 && lane<35){ int d=lane-32; atomicAdd(&outf[sA*3+d], u3c[usA*3+d]*pA); }
        if (vB){
            if (lane<3) atomicAdd(&outf[rB*3+lane], -u3c[usB*3+lane]*pB);
            else if (lane>=32 && lane<35){ int d=lane-32; atomicAdd(&outf[sB*3+d], u3c[usB*3+d]*pB); }
        }
    }
}

extern "C" void kernel_launch(void* const* d_in, const int* in_sizes, int n_in,
                              void* d_out, int out_size, void* d_ws, size_t ws_size,
                              hipStream_t stream)
{
    (void)in_sizes; (void)n_in; (void)out_size; (void)ws_size;
    const float* pos    = (const float*)d_in[0];
    const float* x      = (const float*)d_in[1];
    const float* shifts = (const float*)d_in[2];
    const float* W_embed= (const float*)d_in[3];
    const float* W_up   = (const float*)d_in[4];
    const float* Wm1    = (const float*)d_in[5];
    const float* Wm2    = (const float*)d_in[6];
    const float* Wm3    = (const float*)d_in[7];
    const float* W_out  = (const float*)d_in[8];
    const float* W_sc   = (const float*)d_in[9];
    const float* a_sc   = (const float*)d_in[10];
    const float* w_poly = (const float*)d_in[11];
    const float* W_prod = (const float*)d_in[12];
    const float* w_r0   = (const float*)d_in[13];
    const float* W_r1   = (const float*)d_in[14];
    const float* w_r2   = (const float*)d_in[15];
    const int*   ei     = (const int*)d_in[16];
    const int*   batch  = (const int*)d_in[17];
    float* out = (float*)d_out;

    float* F = (float*)d_ws;
    float* agg0 = F; F += NN*64;
    float* agg1 = F; F += NN*64;
    float* ghb  = F; F += NN*64;
    int* ecount = (int*)F; F += 4;
    float* u3c  = F; F += 3*EE;
    float* frc  = F; F += 8*EE;
    float* dfrc = F; F += 8*EE;
    float* t2b0 = F; F += (size_t)EE*64;
    float* t2b1 = F; F += (size_t)EE*64;
    float* w0b1 = F; F += (size_t)EE*64;
    float* h1   = F; F += NN*64;
    float* nf1  = F; F += NN*64;
    float* s0   = F; F += NN*64;
    float* gagg1= F; F += NN*64;
    float* gagg0= F; F += NN*64;
    float* gacc = F; F += NN*64;
    float* T0   = F; F += ZZ*64;
    float* SC0  = F; F += ZZ*64;
    float* W3z  = F; F += 2*64*64;
    int* spec   = (int*)F; F += NN;
    int* esrc   = (int*)F; F += EE;
    int* edst   = (int*)F; F += EE;

    const float* U0 = W_up;           const float* U1 = W_up   + 4*64*64;
    const float* O0 = W_out;          const float* O1 = W_out  + 4*64*64;
    const float* S0w= W_sc;           const float* S1w= W_sc   + 4*64*64;
    const float* P0 = W_prod;         const float* P1 = W_prod + 4*64*64;
    const float* M1_0=Wm1,  *M1_1=Wm1+8*64;
    const float* M2_0=Wm2,  *M2_1=Wm2+64*64;
    const float* asc1=a_sc+ZZ*64;
    const float* pl0=w_poly, *pl1=w_poly+3*64;
    float* W3z0 = W3z; float* W3z1 = W3z + 64*64;

    k_zero<<<1, 256, 0, stream>>>(ecount, out);
    k_geom<<<GB_ZERO, 256, 0, stream>>>(pos, shifts, ei, x, W_embed, U0, S0w, a_sc, Wm3,
                                        spec, u3c, frc, dfrc, esrc, edst, ecount,
                                        T0, SC0, W3z, (float4*)d_ws, out);

    // forward
    k_edge_fwd<0><<<512,256,0,stream>>>(frc, esrc, edst, ecount, spec, T0, nullptr,
                                        M1_0, M2_0, W3z0, agg0, t2b0, nullptr);
    k_node_fwd0<<<500,256,0,stream>>>(agg0, SC0, spec, batch, O0, P0, U1, pl0, w_r0,
                                      s0, nf1, h1, out);
    k_edge_fwd<1><<<512,256,0,stream>>>(frc, esrc, edst, ecount, spec, nullptr, h1,
                                        M1_1, M2_1, W3z1, agg1, t2b1, w0b1);
    k_node1<<<500,256,0,stream>>>(agg1, nf1, spec, batch, O1, P1, S1w, asc1, pl1,
                                  W_r1, w_r2, out, gagg1, gacc);

    // backward
    k_edge_bwd<1><<<512,256,0,stream>>>(frc, dfrc, u3c, esrc, edst, ecount, spec, nullptr, h1,
                                        gagg1, t2b1, w0b1, M1_1, M2_1, W3z1, ghb, out);
    k_bnode0<<<500,256,0,stream>>>(ghb, gacc, U1, w_r0, s0, O0, P0, pl0, gagg0);
    k_edge_bwd<0><<<512,256,0,stream>>>(frc, dfrc, u3c, esrc, edst, ecount, spec, T0, nullptr,
                                        gagg0, t2b0, nullptr, M1_0, M2_0, W3z0, nullptr, out);
}

// Round 11
// 154.039 us; speedup vs baseline: 1.1153x; 1.1153x over previous
//
#include <hip/hip_runtime.h>
#include <math.h>

constexpr int NN = 4000;
constexpr int EE = 48000;
constexpr int ZZ = 10;
constexpr float RMAX = 5.0f;
constexpr float INV_AVG = 1.0f / 12.0f;

// geom role-block layout
constexpr int GB_EDGE = 188;          // [0,188)   edges
constexpr int GB_SPEC = GB_EDGE + 16; // [188,204) species
constexpr int GB_W3Z  = GB_SPEC + 32; // [204,236) Wm3 l=0 gather
constexpr int GB_T0   = GB_W3Z + 3;   // [236,239) per-species tables
constexpr int GB_ZERO = GB_T0 + 64;   // [239,303) zero agg0/agg1/ghb + out force region
constexpr int ZWS_F4  = 3*NN*64/4;
constexpr int ZOUT_F4 = 3*NN/4;

// Register-resident weight kernels: cap occupancy at 2 waves/EU (min AND max)
// so the allocator can use up to 256 VGPRs without spilling to chase occupancy.
#define WEIGHT_KERNEL __global__ __launch_bounds__(256) __attribute__((amdgpu_waves_per_eu(2,2)))

__device__ __forceinline__ float rl(float v, int lane){
    return __uint_as_float(__builtin_amdgcn_readlane(__float_as_uint(v), lane));
}
__device__ __forceinline__ float sigf(float x){ return 1.0f/(1.0f+__expf(-x)); }
__device__ __forceinline__ float siluf(float x){ return x*sigf(x); }
__device__ __forceinline__ float dsiluf(float x){ float s=sigf(x); return s*(1.0f+x*(1.0f-s)); }

__device__ __forceinline__ void pin64(float (&W)[64]){
#pragma unroll
    for (int i=0;i<64;i++) asm volatile("" : "+v"(W[i]));
}
__device__ __forceinline__ void pin8(float (&W)[8]){
#pragma unroll
    for (int i=0;i<8;i++) asm volatile("" : "+v"(W[i]));
}

// wave-uniform activation pointer: s_load + v_fmac(s, v)
__device__ __forceinline__ float bmv_s(const float* act, const float (&W)[64]){
    float a0=0.f,a1=0.f,a2=0.f,a3=0.f;
#pragma unroll
    for (int k=0;k<64;k+=4){
        a0 += act[k+0]*W[k+0];
        a1 += act[k+1]*W[k+1];
        a2 += act[k+2]*W[k+2];
        a3 += act[k+3]*W[k+3];
    }
    return (a0+a1)+(a2+a3);
}
// per-lane value broadcast via per-wave LDS slice
__device__ __forceinline__ float bmv_lds(float v, const float (&W)[64], float* slice, int lane){
    slice[lane] = v;
    float a0=0.f,a1=0.f,a2=0.f,a3=0.f;
#pragma unroll
    for (int k=0;k<64;k+=4){
        float4 a = *reinterpret_cast<const float4*>(slice + k);
        a0 += a.x*W[k+0];
        a1 += a.y*W[k+1];
        a2 += a.z*W[k+2];
        a3 += a.w*W[k+3];
    }
    return (a0+a1)+(a2+a3);
}
__device__ __forceinline__ void load_row64(const float* __restrict__ p, float (&W)[64]){
#pragma unroll
    for (int i=0;i<16;i++){
        float4 v = reinterpret_cast<const float4*>(p)[i];
        W[4*i]=v.x; W[4*i+1]=v.y; W[4*i+2]=v.z; W[4*i+3]=v.w;
    }
}
__device__ __forceinline__ void load_col64(const float* __restrict__ p, int lane, float (&W)[64]){
#pragma unroll
    for (int k=0;k<64;k++) W[k] = p[k*64+lane];
}

// ---------------- tiny zero ----------------
__global__ void k_zero(int* __restrict__ ecount, float* __restrict__ out)
{
    int t = threadIdx.x;
    if (t < 8) out[t] = 0.0f;
    if (t == 8) *ecount = 0;
}

// ---------------- geometry/compaction + spec + precompute + big zero ----------------
__global__ void k_geom(const float* __restrict__ pos, const float* __restrict__ shifts,
                       const int* __restrict__ ei, const float* __restrict__ x,
                       const float* __restrict__ WE, const float* __restrict__ W_up,
                       const float* __restrict__ W_sc, const float* __restrict__ a_sc,
                       const float* __restrict__ Wm3,
                       int* __restrict__ spec,
                       float* __restrict__ u3c, float* __restrict__ frc, float* __restrict__ dfrc,
                       int* __restrict__ esrc, int* __restrict__ edst, int* __restrict__ ecount,
                       float* __restrict__ T0, float* __restrict__ SC0, float* __restrict__ W3z,
                       float4* __restrict__ zws, float* __restrict__ out)
{
    int b = blockIdx.x;
    if (b >= GB_ZERO) return;
    if (b >= GB_T0){
        float4 z4 = make_float4(0.f,0.f,0.f,0.f);
        float4* zout = (float4*)(out + 8 + NN);
        for (int i=(b-GB_T0)*256 + threadIdx.x; i < ZWS_F4 + ZOUT_F4; i += 64*256){
            if (i < ZWS_F4) zws[i] = z4;
            else zout[i-ZWS_F4] = z4;
        }
        return;
    }
    if (b >= GB_W3Z){
        int wv = (b-GB_W3Z)*4 + (threadIdx.x>>6);
        int lane = threadIdx.x & 63;
        if (wv < ZZ){
            float wev = WE[wv*64 + lane];
            float t=0.f, sc=0.f;
#pragma unroll
            for (int c=0;c<64;c++){
                float w = rl(wev,c);
                t  += w*W_up[c*64+lane];
                sc += w*W_sc[c*64+lane];
            }
            T0[wv*64+lane]  = t;
            SC0[wv*64+lane] = sc * a_sc[wv*64+lane];
        }
        return;
    }
    if (b >= GB_SPEC){
        int idx = (b-GB_SPEC)*256 + threadIdx.x;
        int l = idx >> 12;
        int kc = idx & 4095;
        int k = kc >> 6, c = kc & 63;
        W3z[idx] = Wm3[l*64*256 + k*256 + 4*c];
        return;
    }
    if (b >= GB_EDGE){
        int n = (b-GB_EDGE)*256 + threadIdx.x;
        if (n < NN){
            int sp = 0;
#pragma unroll
            for (int j=0;j<ZZ;j++) if (x[n*ZZ+j] > 0.5f) sp = j;
            spec[n] = sp;
        }
        return;
    }
    int e = b*256 + threadIdx.x;
    if (e >= EE) return;
    int s = ei[e], r = ei[EE+e];
    float vx = pos[r*3+0]-pos[s*3+0]+shifts[e*3+0];
    float vy = pos[r*3+1]-pos[s*3+1]+shifts[e*3+1];
    float vz = pos[r*3+2]-pos[s*3+2]+shifts[e*3+2];
    float rr = sqrtf(vx*vx+vy*vy+vz*vz);
    float u = rr*(1.0f/RMAX);
    if (u >= 1.0f) return;
    int slot = atomicAdd(ecount, 1);
    esrc[slot]=s; edst[slot]=r;
    float inv = 1.0f/rr;
    u3c[slot*3+0]=vx*inv; u3c[slot*3+1]=vy*inv; u3c[slot*3+2]=vz*inv;
    float u2=u*u, u4=u2*u2, u5=u4*u;
    float env  = 1.0f - 21.0f*u5 + 35.0f*u5*u - 15.0f*u5*u2;
    float om   = 1.0f-u;
    float denv = -21.0f*u4*om*om;
    const float A = 0.6324555320336759f;
    const float K1 = 3.14159265358979f/RMAX;
    float a  = K1*rr;
    float s1 = __sinf(a), c1 = __cosf(a);
    float sp = 0.0f, cp = 1.0f, sn = s1, cn = c1;
#pragma unroll
    for (int n=1;n<=8;n++){
        float k = (float)n*K1;
        float bess  = A*sn*inv;
        float dbess = A*(k*cn - sn*inv)*inv;
        frc [slot*8+n-1] = bess*env;
        dfrc[slot*8+n-1] = dbess*env + bess*denv;
        float s2 = 2.0f*c1*sn - sp; sp=sn; sn=s2;
        float c2 = 2.0f*c1*cn - cp; cp=cn; cn=c2;
    }
}

// ---------------- edge MLP forward ----------------
template<int L>
WEIGHT_KERNEL
void k_edge_fwd(const float* __restrict__ frc, const int* __restrict__ esrc,
                const int* __restrict__ edst, const int* __restrict__ ecount,
                const int* __restrict__ spec, const float* __restrict__ T0,
                const float* __restrict__ h1,
                const float* __restrict__ W1, const float* __restrict__ W2,
                const float* __restrict__ W3z,
                float* __restrict__ agg, float* __restrict__ t2b,
                float* __restrict__ w0b)
{
    __shared__ float sact[4][64];
    int lane = threadIdx.x & 63;
    float* slice = sact[threadIdx.x>>6];
    int wid  = (blockIdx.x*256 + threadIdx.x) >> 6;
    int nw   = gridDim.x*4;
    int cnt  = ecount[0];
    float W1c[8], W2c[64], W3c[64];
#pragma unroll
    for (int j=0;j<8;j++) W1c[j] = W1[j*64+lane];
    load_col64(W2,  lane, W2c);
    load_col64(W3z, lane, W3c);
    pin8(W1c); pin64(W2c); pin64(W3c);
    for (int slot=wid; slot<cnt; slot+=nw){
        int us = __builtin_amdgcn_readfirstlane(slot);
        int s = esrc[us], r = edst[us];
        const float* fn = frc + us*8;          // uniform -> s_load
        float t1=0.f;
#pragma unroll
        for (int j=0;j<8;j++) t1 += fn[j]*W1c[j];
        float t2 = bmv_lds(siluf(t1), W2c, slice, lane);
        t2b[(size_t)us*64+lane] = t2;
        float w0 = bmv_lds(siluf(t2), W3c, slice, lane);
        if (L==1) w0b[(size_t)us*64+lane] = w0;
        float h = (L==0) ? T0[spec[s]*64+lane] : h1[s*64+lane];
        atomicAdd(&agg[r*64+lane], w0*h*INV_AVG);
    }
}

// ---------------- node fwd layer0 ----------------
WEIGHT_KERNEL
void k_node_fwd0(const float* __restrict__ agg, const float* __restrict__ SC0,
                 const int* __restrict__ spec, const int* __restrict__ batch,
                 const float* __restrict__ Wout, const float* __restrict__ Wprod,
                 const float* __restrict__ Wup1, const float* __restrict__ poly,
                 const float* __restrict__ wr0,
                 float* __restrict__ s0, float* __restrict__ nf1,
                 float* __restrict__ h1, float* __restrict__ out)
{
    __shared__ float part[8];
    __shared__ float sact[4][64];
    if (threadIdx.x < 8) part[threadIdx.x] = 0.f;
    __syncthreads();
    int lane = threadIdx.x & 63;
    float* slice = sact[threadIdx.x>>6];
    int wid = (blockIdx.x*256 + threadIdx.x) >> 6;
    int nw  = gridDim.x*4;
    float WA[64], WB[64], WC[64];
    load_col64(Wout, lane, WA);
    load_col64(Wprod,lane, WB);
    load_col64(Wup1, lane, WC);
    pin64(WA); pin64(WB); pin64(WC);
    float p0=poly[lane], p1=poly[64+lane], p2=poly[128+lane];
    float w0r = wr0[lane];
    for (int nn=wid; nn<NN; nn+=nw){
        int n = __builtin_amdgcn_readfirstlane(nn);
        const float* an = agg + n*64;          // uniform -> s_load
        float s  = bmv_s(an, WA);
        float gate = p0 + p1*s + p2*s*s;
        float nf = bmv_lds(s*gate, WB, slice, lane) + SC0[spec[n]*64+lane];
        s0 [n*64+lane] = s;
        nf1[n*64+lane] = nf;
        h1 [n*64+lane] = bmv_lds(nf, WC, slice, lane);
        float ne = nf*w0r;
#pragma unroll
        for (int off=32;off;off>>=1) ne += __shfl_xor(ne,off);
        if (lane==0){ out[8+n] = ne; atomicAdd(&part[batch[n]], ne); }
    }
    __syncthreads();
    if (threadIdx.x < 8) atomicAdd(&out[threadIdx.x], part[threadIdx.x]);
}

// ---------------- node fwd layer1 ----------------
WEIGHT_KERNEL
void k_node_fwd1(const float* __restrict__ agg, const float* __restrict__ nf1,
                 const int* __restrict__ spec, const float* __restrict__ Wout,
                 const float* __restrict__ Wprod, const float* __restrict__ Wsc,
                 const float* __restrict__ asc, const float* __restrict__ poly,
                 float* __restrict__ s1, float* __restrict__ nf2)
{
    __shared__ float sact[4][64];
    int lane = threadIdx.x & 63;
    float* slice = sact[threadIdx.x>>6];
    int wid = (blockIdx.x*256 + threadIdx.x) >> 6;
    int nw  = gridDim.x*4;
    float Oc[64], Pc[64], Sc[64];
    load_col64(Wout, lane, Oc);
    load_col64(Wprod,lane, Pc);
    load_col64(Wsc,  lane, Sc);
    pin64(Oc); pin64(Pc); pin64(Sc);
    float p0=poly[lane], p1=poly[64+lane], p2=poly[128+lane];
    for (int nn=wid; nn<NN; nn+=nw){
        int n = __builtin_amdgcn_readfirstlane(nn);
        const float* an  = agg + n*64;         // uniform
        const float* nfn = nf1 + n*64;         // uniform
        float s   = bmv_s(an, Oc);
        float scp = bmv_s(nfn, Sc);
        float gate = p0 + p1*s + p2*s*s;
        float nf  = bmv_lds(s*gate, Pc, slice, lane) + scp*asc[spec[n]*64+lane];
        s1 [n*64+lane] = s;
        nf2[n*64+lane] = nf;
    }
}

// ---------------- readout layer1 ----------------
WEIGHT_KERNEL
void k_read1(const float* __restrict__ nf2, const int* __restrict__ batch,
             const float* __restrict__ Wr1, const float* __restrict__ wr2,
             float* __restrict__ out, float* __restrict__ gnf2)
{
    __shared__ float part[8];
    __shared__ float sact[4][64];
    if (threadIdx.x < 8) part[threadIdx.x] = 0.f;
    __syncthreads();
    int lane = threadIdx.x & 63;
    float* slice = sact[threadIdx.x>>6];
    int wid = (blockIdx.x*256 + threadIdx.x) >> 6;
    int nw  = gridDim.x*4;
    int j = lane & 15;
    float Wcol[64];
#pragma unroll
    for (int c=0;c<64;c++) Wcol[c] = Wr1[c*16 + j];
    pin64(Wcol);
    float Wrow[16];
#pragma unroll
    for (int i=0;i<4;i++){
        float4 v = reinterpret_cast<const float4*>(Wr1 + lane*16)[i];
        Wrow[4*i]=v.x; Wrow[4*i+1]=v.y; Wrow[4*i+2]=v.z; Wrow[4*i+3]=v.w;
    }
    float w2 = wr2[j];
    for (int nn=wid; nn<NN; nn+=nw){
        int n = __builtin_amdgcn_readfirstlane(nn);
        const float* nfn = nf2 + n*64;         // uniform
        float z  = bmv_s(nfn, Wcol);           // z_{lane&15}, replicated 4x
        float ne = siluf(z)*w2;
#pragma unroll
        for (int off=32;off;off>>=1) ne += __shfl_xor(ne,off);
        ne *= 0.25f;
        float gz = w2*dsiluf(z);
        slice[lane] = gz;
        float g = 0.f;
#pragma unroll
        for (int jj=0;jj<16;jj+=4){
            float4 a = *reinterpret_cast<const float4*>(slice + jj);
            g += a.x*Wrow[jj] + a.y*Wrow[jj+1] + a.z*Wrow[jj+2] + a.w*Wrow[jj+3];
        }
        gnf2[n*64+lane] = g;
        if (lane==0){ out[8+n] += ne; atomicAdd(&part[batch[n]], ne); }
    }
    __syncthreads();
    if (threadIdx.x < 8) atomicAdd(&out[threadIdx.x], part[threadIdx.x]);
}

// ---------------- backward node layer1 ----------------
WEIGHT_KERNEL
void k_bnode1(const float* __restrict__ gin, const float* __restrict__ sbuf,
              const float* __restrict__ Wout, const float* __restrict__ Wprod,
              const float* __restrict__ Wsc, const float* __restrict__ asc,
              const int* __restrict__ spec, const float* __restrict__ poly,
              float* __restrict__ gagg, float* __restrict__ gsc)
{
    __shared__ float sact[4][64];
    int lane = threadIdx.x & 63;
    float* slice = sact[threadIdx.x>>6];
    int wid = (blockIdx.x*256 + threadIdx.x) >> 6;
    int nw  = gridDim.x*4;
    float Pr[64], Or[64], Sr[64];
    load_row64(Wprod + lane*64, Pr);
    load_row64(Wout  + lane*64, Or);
    load_row64(Wsc   + lane*64, Sr);
    pin64(Pr); pin64(Or); pin64(Sr);
    float p0=poly[lane], p1=poly[64+lane], p2=poly[128+lane];
    for (int nn=wid; nn<NN; nn+=nw){
        int n = __builtin_amdgcn_readfirstlane(nn);
        const float* gn = gin + n*64;          // uniform
        float gv = bmv_s(gn, Pr);
        float s  = sbuf[n*64+lane];
        float gate = p0 + p1*s + p2*s*s;
        float gs = gv*(gate + s*(p1 + 2.0f*p2*s));
        gagg[n*64+lane] = bmv_lds(gs, Or, slice, lane);
        const float* ascn = asc + spec[n]*64;  // uniform
        float a0=0.f,a1=0.f,a2=0.f,a3=0.f;
#pragma unroll
        for (int k=0;k<64;k+=4){
            a0 += (gn[k+0]*ascn[k+0])*Sr[k+0];
            a1 += (gn[k+1]*ascn[k+1])*Sr[k+1];
            a2 += (gn[k+2]*ascn[k+2])*Sr[k+2];
            a3 += (gn[k+3]*ascn[k+3])*Sr[k+3];
        }
        gsc[n*64+lane] = (a0+a1)+(a2+a3);
    }
}

// ---------------- fused gnf1 assembly + node bwd layer0 ----------------
WEIGHT_KERNEL
void k_bnode0(const float* __restrict__ ghb, const float* __restrict__ gacc,
              const float* __restrict__ Wup1, const float* __restrict__ wr0,
              const float* __restrict__ sbuf, const float* __restrict__ Wout,
              const float* __restrict__ Wprod, const float* __restrict__ poly,
              float* __restrict__ gagg)
{
    __shared__ float sact[4][64];
    int lane = threadIdx.x & 63;
    float* slice = sact[threadIdx.x>>6];
    int wid = (blockIdx.x*256 + threadIdx.x) >> 6;
    int nw  = gridDim.x*4;
    float Ur[64], Pr[64], Or[64];
    load_row64(Wup1 + lane*64, Ur);
    load_row64(Wprod+ lane*64, Pr);
    load_row64(Wout + lane*64, Or);
    pin64(Ur); pin64(Pr); pin64(Or);
    float p0=poly[lane], p1=poly[64+lane], p2=poly[128+lane];
    float w0r = wr0[lane];
    for (int nn=wid; nn<NN; nn+=nw){
        int n = __builtin_amdgcn_readfirstlane(nn);
        const float* ghn = ghb + n*64;         // uniform
        float g  = bmv_s(ghn, Ur) + gacc[n*64+lane] + w0r;
        float gv = bmv_lds(g, Pr, slice, lane);
        float s  = sbuf[n*64+lane];
        float gate = p0 + p1*s + p2*s*s;
        float gs = gv*(gate + s*(p1 + 2.0f*p2*s));
        gagg[n*64+lane] = bmv_lds(gs, Or, slice, lane);
    }
}

// ---------------- edge bwd ----------------
template<int L>
WEIGHT_KERNEL
void k_edge_bwd(const float* __restrict__ frc, const float* __restrict__ dfrc,
                const float* __restrict__ u3c, const int* __restrict__ esrc,
                const int* __restrict__ edst, const int* __restrict__ ecount,
                const int* __restrict__ spec, const float* __restrict__ T0,
                const float* __restrict__ h1, const float* __restrict__ gagg,
                const float* __restrict__ t2b, const float* __restrict__ w0b,
                const float* __restrict__ W1, const float* __restrict__ W2,
                const float* __restrict__ W3z,
                float* __restrict__ ghb, float* __restrict__ out)
{
    __shared__ float sact[4][64];
    int lane = threadIdx.x & 63;
    float* slice = sact[threadIdx.x>>6];
    int wid  = (blockIdx.x*256 + threadIdx.x) >> 6;
    int nw   = gridDim.x*4;
    int cnt  = ecount[0];
    float* outf = out + 8 + NN;
    float W3r[64], W2r[64], W1c[8];
    load_row64(W3z + lane*64, W3r);
    load_row64(W2  + lane*64, W2r);
#pragma unroll
    for (int j=0;j<8;j++) W1c[j] = W1[j*64+lane];
    pin64(W3r); pin64(W2r); pin8(W1c);
    for (int slot=wid; slot<cnt; slot+=nw){
        int us = __builtin_amdgcn_readfirstlane(slot);
        int s = esrc[us], r = edst[us];
        float gm = gagg[r*64+lane]*INV_AVG;
        float h  = (L==0) ? T0[spec[s]*64+lane] : h1[s*64+lane];
        if (L==1) atomicAdd(&ghb[s*64+lane], gm*w0b[(size_t)us*64+lane]);
        float ga2 = bmv_lds(gm*h, W3r, slice, lane);
        float gt2 = ga2*dsiluf(t2b[(size_t)us*64+lane]);
        float ga1 = bmv_lds(gt2, W2r, slice, lane);
        const float* fn  = frc  + us*8;        // uniform
        const float* dfn = dfrc + us*8;        // uniform
        float t1=0.f, wd=0.f;
#pragma unroll
        for (int j=0;j<8;j++){ t1 += fn[j]*W1c[j]; wd += dfn[j]*W1c[j]; }
        float p = ga1*dsiluf(t1)*wd;
#pragma unroll
        for (int off=32;off;off>>=1) p += __shfl_xor(p,off);
        if (lane<3) atomicAdd(&outf[r*3+lane], -u3c[us*3+lane]*p);
        else if (lane>=32 && lane<35){ int d=lane-32; atomicAdd(&outf[s*3+d], u3c[us*3+d]*p); }
    }
}

extern "C" void kernel_launch(void* const* d_in, const int* in_sizes, int n_in,
                              void* d_out, int out_size, void* d_ws, size_t ws_size,
                              hipStream_t stream)
{
    (void)in_sizes; (void)n_in; (void)out_size; (void)ws_size;
    const float* pos    = (const float*)d_in[0];
    const float* x      = (const float*)d_in[1];
    const float* shifts = (const float*)d_in[2];
    const float* W_embed= (const float*)d_in[3];
    const float* W_up   = (const float*)d_in[4];
    const float* Wm1    = (const float*)d_in[5];
    const float* Wm2    = (const float*)d_in[6];
    const float* Wm3    = (const float*)d_in[7];
    const float* W_out  = (const float*)d_in[8];
    const float* W_sc   = (const float*)d_in[9];
    const float* a_sc   = (const float*)d_in[10];
    const float* w_poly = (const float*)d_in[11];
    const float* W_prod = (const float*)d_in[12];
    const float* w_r0   = (const float*)d_in[13];
    const float* W_r1   = (const float*)d_in[14];
    const float* w_r2   = (const float*)d_in[15];
    const int*   ei     = (const int*)d_in[16];
    const int*   batch  = (const int*)d_in[17];
    float* out = (float*)d_out;

    float* F = (float*)d_ws;
    float* agg0 = F; F += NN*64;
    float* agg1 = F; F += NN*64;
    float* ghb  = F; F += NN*64;
    int* ecount = (int*)F; F += 4;
    float* u3c  = F; F += 3*EE;
    float* frc  = F; F += 8*EE;
    float* dfrc = F; F += 8*EE;
    float* t2b0 = F; F += (size_t)EE*64;
    float* t2b1 = F; F += (size_t)EE*64;
    float* w0b1 = F; F += (size_t)EE*64;
    float* h1   = F; F += NN*64;
    float* nf1  = F; F += NN*64;
    float* nf2  = F; F += NN*64;
    float* s0   = F; F += NN*64;
    float* s1   = F; F += NN*64;
    float* gnf2 = F; F += NN*64;
    float* gagg1= F; F += NN*64;
    float* gagg0= F; F += NN*64;
    float* gacc = F; F += NN*64;
    float* T0   = F; F += ZZ*64;
    float* SC0  = F; F += ZZ*64;
    float* W3z  = F; F += 2*64*64;
    int* spec   = (int*)F; F += NN;
    int* esrc   = (int*)F; F += EE;
    int* edst   = (int*)F; F += EE;

    const float* U0 = W_up;           const float* U1 = W_up   + 4*64*64;
    const float* O0 = W_out;          const float* O1 = W_out  + 4*64*64;
    const float* S0w= W_sc;           const float* S1w= W_sc   + 4*64*64;
    const float* P0 = W_prod;         const float* P1 = W_prod + 4*64*64;
    const float* M1_0=Wm1,  *M1_1=Wm1+8*64;
    const float* M2_0=Wm2,  *M2_1=Wm2+64*64;
    const float* asc1=a_sc+ZZ*64;
    const float* pl0=w_poly, *pl1=w_poly+3*64;
    float* W3z0 = W3z; float* W3z1 = W3z + 64*64;

    k_zero<<<1, 256, 0, stream>>>(ecount, out);
    k_geom<<<GB_ZERO, 256, 0, stream>>>(pos, shifts, ei, x, W_embed, U0, S0w, a_sc, Wm3,
                                        spec, u3c, frc, dfrc, esrc, edst, ecount,
                                        T0, SC0, W3z, (float4*)d_ws, out);

    // forward
    k_edge_fwd<0><<<512,256,0,stream>>>(frc, esrc, edst, ecount, spec, T0, nullptr,
                                        M1_0, M2_0, W3z0, agg0, t2b0, nullptr);
    k_node_fwd0<<<500,256,0,stream>>>(agg0, SC0, spec, batch, O0, P0, U1, pl0, w_r0,
                                      s0, nf1, h1, out);
    k_edge_fwd<1><<<512,256,0,stream>>>(frc, esrc, edst, ecount, spec, nullptr, h1,
                                        M1_1, M2_1, W3z1, agg1, t2b1, w0b1);
    k_node_fwd1<<<500,256,0,stream>>>(agg1, nf1, spec, O1, P1, S1w, asc1, pl1, s1, nf2);
    k_read1<<<500,256,0,stream>>>(nf2, batch, W_r1, w_r2, out, gnf2);

    // backward
    k_bnode1<<<500,256,0,stream>>>(gnf2, s1, O1, P1, S1w, asc1, spec, pl1, gagg1, gacc);
    k_edge_bwd<1><<<512,256,0,stream>>>(frc, dfrc, u3c, esrc, edst, ecount, spec, nullptr, h1,
                                        gagg1, t2b1, w0b1, M1_1, M2_1, W3z1, ghb, out);
    k_bnode0<<<500,256,0,stream>>>(ghb, gacc, U1, w_r0, s0, O0, P0, pl0, gagg0);
    k_edge_bwd<0><<<512,256,0,stream>>>(frc, dfrc, u3c, esrc, edst, ecount, spec, T0, nullptr,
                                        gagg0, t2b0, nullptr, M1_0, M2_0, W3z0, nullptr, out);
}